// Round 1
// baseline (190.709 us; speedup 1.0000x reference)
//
#include <hip/hip_runtime.h>
#include <math.h>

#define N_EDGES   1000000
#define THR_LO    0.6f
#define THR_HI    0.8f
#define LOG_CLAMP -100.0f

// acc layout in d_ws: [0]=sim_sum, [1]=disim_sum, [2]=n_sim, [3]=n_disim
__global__ void __launch_bounds__(256)
edge_loss_kernel(const int2* __restrict__ edges,
                 const float* __restrict__ probas,
                 const float4* __restrict__ feats,   // [N_NODES][16] float4
                 float* __restrict__ acc) {
    int tid    = blockIdx.x * blockDim.x + threadIdx.x;
    int stride = gridDim.x * blockDim.x;

    float sim = 0.f, disim = 0.f, ns = 0.f, nd = 0.f;

    for (int e = tid; e < N_EDGES; e += stride) {
        int2 ij = edges[e];
        float pi = probas[ij.x];
        float pj = probas[ij.y];
        bool msim = (pi >= THR_HI) & (pj >= THR_HI);
        bool mdis = ((pi >= THR_HI) & (pj < THR_LO)) |
                    ((pj >= THR_HI) & (pi < THR_LO));
        if (msim | mdis) {
            const float4* fi = feats + (size_t)ij.x * 16;
            const float4* fj = feats + (size_t)ij.y * 16;
            float s = 0.f;
            #pragma unroll
            for (int k = 0; k < 16; ++k) {
                float4 a = fi[k];
                float4 b = fj[k];
                float dx = a.x - b.x, dy = a.y - b.y;
                float dz = a.z - b.z, dw = a.w - b.w;
                s += dx * dx + dy * dy + dz * dz + dw * dw;
            }
            float d = sqrtf(s);
            if (msim) {
                // -max(log(exp(-d)), -100) == min(d, 100)
                sim += fminf(d, 100.0f);
                ns  += 1.0f;
            }
            if (mdis) {
                float p = expf(-d);
                float l = log1pf(-p);            // log(1 - p), accurate for tiny p
                disim += -fmaxf(l, LOG_CLAMP);
                nd    += 1.0f;
            }
        }
    }

    // wave-64 shuffle reduction
    #pragma unroll
    for (int off = 32; off > 0; off >>= 1) {
        sim   += __shfl_down(sim,   off);
        disim += __shfl_down(disim, off);
        ns    += __shfl_down(ns,    off);
        nd    += __shfl_down(nd,    off);
    }

    __shared__ float lds[4][4];   // 4 waves per 256-thread block
    int lane = threadIdx.x & 63;
    int wave = threadIdx.x >> 6;
    if (lane == 0) {
        lds[wave][0] = sim;
        lds[wave][1] = disim;
        lds[wave][2] = ns;
        lds[wave][3] = nd;
    }
    __syncthreads();
    if (threadIdx.x == 0) {
        float a = 0.f, b = 0.f, c = 0.f, d4 = 0.f;
        int nw = blockDim.x >> 6;
        for (int w = 0; w < nw; ++w) {
            a  += lds[w][0];
            b  += lds[w][1];
            c  += lds[w][2];
            d4 += lds[w][3];
        }
        atomicAdd(&acc[0], a);
        atomicAdd(&acc[1], b);
        atomicAdd(&acc[2], c);
        atomicAdd(&acc[3], d4);
    }
}

__global__ void finalize_kernel(const float* __restrict__ acc,
                                float* __restrict__ out) {
    float sim_sum   = acc[0];
    float disim_sum = acc[1];
    float n_sim     = acc[2];
    float n_disim   = acc[3];
    float total     = n_sim + n_disim;
    float pos_w     = n_disim / total;
    float neg_w     = n_sim / total;
    out[0] = (sim_sum * pos_w + disim_sum * neg_w) / total;
}

extern "C" void kernel_launch(void* const* d_in, const int* in_sizes, int n_in,
                              void* d_out, int out_size, void* d_ws, size_t ws_size,
                              hipStream_t stream) {
    const int*   edges  = (const int*)d_in[0];    // (N_EDGES, 2) int32
    const float* probas = (const float*)d_in[1];  // (N_NODES,)
    const float* feats  = (const float*)d_in[2];  // (N_NODES, 64)
    float* acc = (float*)d_ws;

    hipMemsetAsync(acc, 0, 4 * sizeof(float), stream);

    const int block = 256;
    const int grid  = 2048;   // grid-stride; ~2 edges/thread, 8 blocks/CU
    edge_loss_kernel<<<grid, block, 0, stream>>>(
        (const int2*)edges, probas, (const float4*)feats, acc);

    finalize_kernel<<<1, 1, 0, stream>>>(acc, (float*)d_out);
}